// Round 15
// baseline (215.359 us; speedup 1.0000x reference)
//
#include <hip/hip_runtime.h>
#include <hip/hip_bf16.h>

#define NN 16384
#define DD 256

typedef unsigned short u16;
typedef unsigned int u32;
typedef unsigned char u8;
typedef long i64;
typedef __attribute__((ext_vector_type(8))) int i32x8;
typedef __attribute__((ext_vector_type(4))) float f32x4;

// async global->LDS, 16B per lane; LDS dest = wave-uniform base + lane*16
static __device__ __forceinline__ void gload16(const u8* g, u8* l) {
    __builtin_amdgcn_global_load_lds(
        (const __attribute__((address_space(1))) void*)g,
        (__attribute__((address_space(3))) void*)l,
        16, 0, 0);
}

static __device__ __forceinline__ i32x8 pack4(i64 a, i64 b, i64 c, i64 d) {
    i32x8 v;
    v[0] = (int)a; v[1] = (int)(a >> 32);
    v[2] = (int)b; v[3] = (int)(b >> 32);
    v[4] = (int)c; v[5] = (int)(c >> 32);
    v[6] = (int)d; v[7] = (int)(d >> 32);
    return v;
}

// ---------- kernel 1: fp8 e4m3 convert, pre-swizzled (R12 formulas VERBATIM) ----------
// A8: [pn 256][kc 4][rl 64][64 B], chunk cs at P=cs^((rl^(rl>>2))&3),
//     8B half at (qq&1)^((rl>>3)&1).   (same key formulas as R12's measured-zero walk;
//     panels now 64 rows — keys use only bits 0..3 of rl, unaffected)
// B8: [cb 128][rl 128][256 B], kc-block at kc^((rl>>1)&3), chunk cs at
//     P=cs^((((rl>>2)&1)<<1)|(rl&1)), half same key.  UNCHANGED from R12/R14.
__global__ void prep_kernel(const float* __restrict__ img, const float* __restrict__ txt,
                            u8* __restrict__ A8, u8* __restrict__ B8,
                            float* __restrict__ zbuf /* s_row..s_col 32768 f */,
                            float* __restrict__ out) {
    int gid = blockIdx.x * 256 + threadIdx.x;          // 0 .. 1048575  (N*D/4)
    float4 va = ((const float4*)img)[gid];
    float4 vb = ((const float4*)txt)[gid];
    const float S = 1.44269504088896f;                  // log2(e) folded into A
    int pa = __builtin_amdgcn_cvt_pk_fp8_f32(va.x * S, va.y * S, 0, false);
    pa     = __builtin_amdgcn_cvt_pk_fp8_f32(va.z * S, va.w * S, pa, true);
    int pb = __builtin_amdgcn_cvt_pk_fp8_f32(vb.x, vb.y, 0, false);
    pb     = __builtin_amdgcn_cvt_pk_fp8_f32(vb.z, vb.w, pb, true);

    const int r  = gid >> 6;            // global row
    const int ko = (gid & 63) << 2;     // k-byte offset 0..255, step 4
    const int J  = ko >> 3;             // 8-byte slot 0..31
    const int u  = ko & 7;              // 0 or 4
    const int kc = J >> 3;
    const int s  = (J >> 2) & 1;
    const int qq = J & 3;
    const int cs = (s << 1) | (qq >> 1);
    // A: 64-row panels
    {
        const int rl = r & 63;
        const int pn = r >> 6;
        const int hh = (qq & 1) ^ ((rl >> 3) & 1);
        const int P  = cs ^ ((rl ^ (rl >> 2)) & 3);
        *(u32*)(A8 + ((size_t)pn << 14) + (kc << 12) + (rl << 6)
                   + (P << 4) + (hh << 3) + u) = (u32)pa;
    }
    // B: 128-row panels (unchanged)
    {
        const int rl = r & 127;
        const int pn = r >> 7;
        const int hh = (qq & 1) ^ ((rl >> 3) & 1);
        const int kp = kc ^ ((rl >> 1) & 3);
        const int P  = cs ^ ((((rl >> 2) & 1) << 1) | (rl & 1));
        *(u32*)(B8 + ((size_t)pn << 15) + (rl << 8) + (kp << 6)
                   + (P << 4) + (hh << 3) + u) = (u32)pb;
    }
    if (gid < 32768) zbuf[gid] = 0.0f;
    if (gid == 0) out[0] = 0.0f;
}

// ---------- kernel 2: fused MX-fp8 GEMM (16x16x128 scaled) + exp2 + sums + diag ----------
// R14 with ONE structural change: 64-row A panels -> 16 KB A + 32 KB B = 48 KB
// LDS -> 3 blocks/CU (12 waves/CU vs 8) for latency hiding, the binding
// constraint per R14's counters (no pipe >41%, occupancy 20%).
// Grid 2048 = 8 jg x 256 bi, bi FAST. Wave = 64 rows x 32 cols (acc 4x2).
// All LDS access patterns keep R12/R14's measured-zero bank walks: A/B swizzle
// keys depend only on m (rb*16 / cb*16 / wc*32 cancel in every mask), addresses
// affine in rb/cb/kc -> immediates. 2 barriers per tile, atomic s_row/s_col.
__global__ __launch_bounds__(256, 3) void gemm_lse_kernel(
        const u8* __restrict__ A8, const u8* __restrict__ B8,
        float* __restrict__ s_row, float* __restrict__ s_col,
        float* __restrict__ diag) {
    __shared__ u8 sA[16384];        // [kc 4][64 rows][64 B]  (pre-swizzled)
    __shared__ u8 sB[32768];        // [128 rows][256 B]      (pre-swizzled)

    const int t = threadIdx.x;
    const int lane = t & 63;
    const int w = t >> 6;           // wc: column quarter 0..3
    const int q = lane >> 4, m = lane & 15;
    const int bi = blockIdx.x & 255;            // FAST: resident blocks share B phase
    const int jg = blockIdx.x >> 8;
    const int row0 = bi << 6;

    // ---- stage A panel ONCE: linear 16 KB copy, 4 rounds x 256 lanes x 16 B
    #pragma unroll
    for (int R = 0; R < 4; ++R)
        gload16(A8 + ((size_t)bi << 14) + (R << 12) + (w << 10) + ((size_t)lane << 4),
                &sA[(R << 12) + (w << 10)]);

    const f32x4 fzero = {0.f, 0.f, 0.f, 0.f};
    f32x4 acc[4][2];
    f32x4 rp[4] = {fzero, fzero, fzero, fzero};   // row partials, whole block

    #pragma unroll 1
    for (int jt = 0; jt < 16; ++jt) {
        const int ct = (jg << 4) + jt;            // column tile index
        const int col0 = ct << 7;
        __syncthreads();   // all waves done computing previous tile from sB
        #pragma unroll
        for (int R = 0; R < 8; ++R)
            gload16(B8 + ((size_t)ct << 15) + (R << 12) + (w << 10) + ((size_t)lane << 4),
                    &sB[(R << 12) + (w << 10)]);
        __syncthreads();   // drains vmcnt -> sB (and sA on jt=0) ready

        // ---- 16 scaled MFMAs per wave per tile, no barriers inside ----
        #pragma unroll
        for (int ki = 0; ki < 2; ++ki) {
            i32x8 av[4], bv[2];
            #pragma unroll
            for (int rb = 0; rb < 4; ++rb) {
                const int rr = (rb << 4) + m;                  // row in 64-panel
                const int ra = (rr ^ (rr >> 2)) & 3;           // = f(m) only
                const int hA = ((q & 1) ^ ((rr >> 3) & 1)) << 3;
                i64 aS[4];
                #pragma unroll
                for (int d = 0; d < 2; ++d) {
                    const int kc = (ki << 1) + d;
                    #pragma unroll
                    for (int e = 0; e < 2; ++e) {
                        const int cs = (e << 1) | (q >> 1);
                        const int PA = cs ^ ra;
                        aS[(d << 1) | e] = *(const i64*)(&sA[(kc << 12) + (rr << 6) + (PA << 4) + hA]);
                    }
                }
                av[rb] = pack4(aS[0], aS[1], aS[2], aS[3]);
            }
            #pragma unroll
            for (int cb = 0; cb < 2; ++cb) {
                const int cr = (w << 5) + (cb << 4) + m;       // col in 128-tile
                const int rbx = (((cr >> 2) & 1) << 1) | (cr & 1);
                const int hB = ((q & 1) ^ ((cr >> 3) & 1)) << 3;
                i64 bS[4];
                #pragma unroll
                for (int d = 0; d < 2; ++d) {
                    const int kc = (ki << 1) + d;
                    const int kp = kc ^ ((cr >> 1) & 3);
                    #pragma unroll
                    for (int e = 0; e < 2; ++e) {
                        const int cs = (e << 1) | (q >> 1);
                        const int PB = cs ^ rbx;
                        bS[(d << 1) | e] = *(const i64*)(&sB[(cr << 8) + (kp << 6) + (PB << 4) + hB]);
                    }
                }
                bv[cb] = pack4(bS[0], bS[1], bS[2], bS[3]);
            }
            if (ki == 0) {
                #pragma unroll
                for (int rb = 0; rb < 4; ++rb)
                    #pragma unroll
                    for (int cb = 0; cb < 2; ++cb)
                        acc[rb][cb] = __builtin_amdgcn_mfma_scale_f32_16x16x128_f8f6f4(
                            av[rb], bv[cb], fzero, 0, 0,
                            0, 0x7F7F7F7F, 0, 0x7F7F7F7F);
            } else {
                #pragma unroll
                for (int rb = 0; rb < 4; ++rb)
                    #pragma unroll
                    for (int cb = 0; cb < 2; ++cb)
                        acc[rb][cb] = __builtin_amdgcn_mfma_scale_f32_16x16x128_f8f6f4(
                            av[rb], bv[cb], acc[rb][cb], 0, 0,
                            0, 0x7F7F7F7F, 0, 0x7F7F7F7F);
            }
        }

        // ---- per-tile epilogue (C/D: col=m, row=q*4+r) ----
        // diag: row global = bi*64+rb*16+q*4+r, col global = ct*128+w*32+cb*16+m.
        // Equal iff ct==bi>>1, (w>>1)==(bi&1), rb==2*(w&1)+cb, m==q*4+r.
        if (ct == (bi >> 1) && (w >> 1) == (bi & 1)) {
            #pragma unroll
            for (int cb = 0; cb < 2; ++cb) {
                const int rb = ((w & 1) << 1) | cb;
                #pragma unroll
                for (int r = 0; r < 4; ++r)
                    if (m == ((q << 2) | r))
                        diag[row0 + (rb << 4) + m] = acc[rb][cb][r];
            }
        }
        #pragma unroll
        for (int rb = 0; rb < 4; ++rb)
            #pragma unroll
            for (int cb = 0; cb < 2; ++cb)
                #pragma unroll
                for (int r = 0; r < 4; ++r)
                    acc[rb][cb][r] = __builtin_amdgcn_exp2f(acc[rb][cb][r] - 144.0f);

        // row partials: pure VALU, reduced once at block end
        #pragma unroll
        for (int rb = 0; rb < 4; ++rb)
            rp[rb] += acc[rb][0] + acc[rb][1];

        // col partials: sum over rb/r, butterfly over q; lanes with q==cb write.
        #pragma unroll
        for (int cb = 0; cb < 2; ++cb) {
            float v = 0.0f;
            #pragma unroll
            for (int rb = 0; rb < 4; ++rb)
                v += (acc[rb][cb][0] + acc[rb][cb][1]) + (acc[rb][cb][2] + acc[rb][cb][3]);
            v += __shfl_xor(v, 16, 64);
            v += __shfl_xor(v, 32, 64);
            if (q == cb)
                atomicAdd(&s_col[col0 + (w << 5) + (cb << 4) + m], v);
        }
    }

    // ---- block-end row reduction: rp[rb][r] is row (rb*16+q*4+r) over this
    // wave's 32 cols, spread across 16 m-lanes. Butterfly over m; lane m==rb*4+r
    // keeps it; each lane then owns row (m>>2)*16 + q*4 + (m&3). 4-way atomic/row.
    float rout = 0.0f;
    #pragma unroll
    for (int rb = 0; rb < 4; ++rb)
        #pragma unroll
        for (int r = 0; r < 4; ++r) {
            float v = rp[rb][r];
            v += __shfl_xor(v, 1, 16);
            v += __shfl_xor(v, 2, 16);
            v += __shfl_xor(v, 4, 16);
            v += __shfl_xor(v, 8, 16);
            if (m == ((rb << 2) | r)) rout = v;
        }
    atomicAdd(&s_row[row0 + ((m >> 2) << 4) + (q << 2) + (m & 3)], rout);
}

// ---------- kernel 3: final reduce (64 blocks, 256 rows each) ----------
__global__ void final_kernel(const float* __restrict__ s_row, const float* __restrict__ s_col,
                             const float* __restrict__ diag, float* __restrict__ out) {
    __shared__ double red[256];
    int t = threadIdx.x;
    int i = blockIdx.x * 256 + t;
    double p = 0.5 * (double)(log2f(s_row[i]) + log2f(s_col[i])) + 144.0 - (double)diag[i];
    red[t] = p;
    __syncthreads();
    for (int s = 128; s > 0; s >>= 1) {
        if (t < s) red[t] += red[t + s];
        __syncthreads();
    }
    if (t == 0) atomicAdd(out, (float)(red[0] * 0.6931471805599453 / (double)NN));
}

// ---------- launch ----------
extern "C" void kernel_launch(void* const* d_in, const int* in_sizes, int n_in,
                              void* d_out, int out_size, void* d_ws, size_t ws_size,
                              hipStream_t stream) {
    const float* img = (const float*)d_in[0];
    const float* txt = (const float*)d_in[1];
    char* ws = (char*)d_ws;
    u8*    A8    = (u8*)ws;                                // 4 MB
    u8*    B8    = (u8*)(ws + 4194304);                    // 4 MB
    float* s_row = (float*)(ws + 8388608);                 // 64 KB
    float* s_col = (float*)(ws + 8388608 + 65536);         // 64 KB
    float* diag  = (float*)(ws + 8388608 + 131072);        // 64 KB
    float* out   = (float*)d_out;

    prep_kernel<<<4096, 256, 0, stream>>>(img, txt, A8, B8, s_row, out);
    gemm_lse_kernel<<<2048, 256, 0, stream>>>(A8, B8, s_row, s_col, diag);
    final_kernel<<<64, 256, 0, stream>>>(s_row, s_col, diag, out);
}